// Round 1
// baseline (1288.402 us; speedup 1.0000x reference)
//
#include <hip/hip_runtime.h>
#include <stdint.h>

// ---------------------------------------------------------------------------
// STGTCN layer: xt = relu(conv1(x)+b1 + sigmoid(conv2(x)+b2) + conv3(x)+b3)
//               x1 = A^T xt (over V), x2 = A^T x1
//               out = PReLU(W_out · concat(xt,x1,x2) + b_out)
// N=32, C=32, V=500 (pad 512), T=96 -> T'=94 (pad 96), C_OUT=64, GC=96
//
// Workspace layout (bf16 h-planes stored as [b=n*32+c][vblk=v/8][l(96)][v%8]
// so that MFMA B-fragments (k = v, 8-contiguous per lane) are 16B groups):
//   xt : S bytes       x1 : S       x2 : S       (S = 1024*64*96*8*2)
//   At : 512*512 bf16 (A^T, zero-padded => no masking in GEMMs)
//   Wp : conv weights fp32 repacked [i][k][conv][c]
//   Wo : w_out bf16 [o][c]
// ---------------------------------------------------------------------------

typedef float  f32x4  __attribute__((ext_vector_type(4)));
typedef float  f32x2  __attribute__((ext_vector_type(2)));
typedef short  bf16x8 __attribute__((ext_vector_type(8)));

static __device__ __forceinline__ unsigned short f2bf(float f) {
    union { float f; unsigned u; } v; v.f = f;
    unsigned u = v.u;
    return (unsigned short)((u + 0x7fffu + ((u >> 16) & 1u)) >> 16);  // RTNE
}

#define WS_S   ((size_t)1024 * 64 * 96 * 8 * 2)   // one bf16 h-plane set
#define AT_B   (512u * 512u * 2u)
#define WP_B   (32u * 3u * 3u * 32u * 4u)

// swizzle of 16B k-slots within a 64B LDS row (kills frag-read bank conflicts)
static __device__ __forceinline__ int swz(int row, int q) {
    return q ^ (row & 3) ^ ((row >> 2) & 3);
}

// ---------------------------------------------------------------------------
// prep: build At (bf16, transposed, zero-padded), Wp (fp32 repack), Wo (bf16)
// ---------------------------------------------------------------------------
__global__ __launch_bounds__(256)
void prep_kernel(const float* __restrict__ A,
                 const float* __restrict__ w1, const float* __restrict__ w2,
                 const float* __restrict__ w3, const float* __restrict__ wout,
                 unsigned short* __restrict__ At, float* __restrict__ Wp,
                 unsigned short* __restrict__ Wo)
{
    int idx = blockIdx.x * 256 + threadIdx.x;
    if (idx < 512 * 512) {
        int w = idx >> 9, v = idx & 511;
        float val = (w < 500 && v < 500) ? A[v * 500 + w] : 0.f;  // At[w][v] = A[v][w]
        At[idx] = f2bf(val);
    } else if (idx < 512 * 512 + 32 * 3 * 3 * 32) {
        int t = idx - 512 * 512;
        int c = t & 31; int r = t >> 5; int conv = r % 3; int ik = r / 3;
        const float* ws = (conv == 0) ? w1 : ((conv == 1) ? w2 : w3);
        Wp[t] = ws[c * 96 + ik];   // Wp[((ik)*3+conv)*32 + c]
    } else if (idx < 512 * 512 + 32 * 3 * 3 * 32 + 64 * 96) {
        int t = idx - (512 * 512 + 32 * 3 * 3 * 32);
        Wo[t] = f2bf(wout[t]);
    }
}

// ---------------------------------------------------------------------------
// conv: fused gated temporal conv. Block = (n, vblk of 8 v). 512 threads.
// thread = (cpair cp, tgroup tg, vquad vq): 2 channels x 12 t' x 2 vv
// packed-f32 math over the channel pair. Output staged in LDS, then stored
// as contiguous 16B rows of xt[b][vblk][l][8].
// ---------------------------------------------------------------------------
__global__ __launch_bounds__(512, 1)
void conv_kernel(const float* __restrict__ x, const float* __restrict__ Wp,
                 const float* __restrict__ b1, const float* __restrict__ b2,
                 const float* __restrict__ b3, unsigned short* __restrict__ xt)
{
    __shared__ unsigned short Xs[8 * 32 * 100];   // bf16 x tile [vv][i][t], t padded to 100
    __shared__ float Wl[32 * 3 * 3 * 32];         // fp32 weights
    __shared__ unsigned short stash[32 * 96 * 8]; // bf16 out tile [c][t'][vv]

    const int n = blockIdx.y;
    const int vblk = blockIdx.x;          // 0..62
    const int tid = threadIdx.x;

    for (int i = tid; i < 32 * 3 * 3 * 32; i += 512) Wl[i] = Wp[i];

    // stage Xs: 256 rows (i,vv) x 96 t, fp32 -> bf16
    for (int s = 0; s < 12; ++s) {
        int fid = tid + s * 512;          // 0..6143
        int seg = fid % 24;               // float4 index within row
        int row = fid / 24;               // 0..255
        int i = row >> 3, vv = row & 7;
        int v = vblk * 8 + vv;
        float4 val = make_float4(0.f, 0.f, 0.f, 0.f);
        if (v < 500)
            val = *(const float4*)(x + (((size_t)n * 32 + i) * 500 + v) * 96 + seg * 4);
        int base = (vv * 32 + i) * 100 + seg * 4;
        unsigned v01 = (unsigned)f2bf(val.x) | ((unsigned)f2bf(val.y) << 16);
        unsigned v23 = (unsigned)f2bf(val.z) | ((unsigned)f2bf(val.w) << 16);
        *(unsigned*)&Xs[base] = v01;
        *(unsigned*)&Xs[base + 2] = v23;
    }
    __syncthreads();

    const int cp = tid & 15, tg = (tid >> 4) & 7, vq = tid >> 7;
    const int c0 = cp * 2, t0 = tg * 12;
    const float bb1x = b1[c0], bb1y = b1[c0 + 1];
    const float bb2x = b2[c0], bb2y = b2[c0 + 1];
    const float bb3x = b3[c0], bb3y = b3[c0 + 1];

    for (int vh = 0; vh < 2; ++vh) {
        const int vv = vq + vh * 4;
        f32x2 acc0[12], acc1[12], acc2[12];
        #pragma unroll
        for (int j = 0; j < 12; ++j) {
            acc0[j] = (f32x2){0.f, 0.f}; acc1[j] = (f32x2){0.f, 0.f}; acc2[j] = (f32x2){0.f, 0.f};
        }
        for (int i = 0; i < 32; ++i) {
            float X[14];
            const unsigned* xp = (const unsigned*)&Xs[(vv * 32 + i) * 100 + t0];
            #pragma unroll
            for (int j = 0; j < 7; ++j) {
                unsigned u = xp[j];
                X[2 * j]     = __uint_as_float(u << 16);
                X[2 * j + 1] = __uint_as_float(u & 0xffff0000u);
            }
            #pragma unroll
            for (int k = 0; k < 3; ++k) {
                const float* wb = &Wl[((i * 3 + k) * 3) * 32 + c0];
                f32x2 w0 = *(const f32x2*)(wb);
                f32x2 w1v = *(const f32x2*)(wb + 32);
                f32x2 w2v = *(const f32x2*)(wb + 64);
                #pragma unroll
                for (int j = 0; j < 12; ++j) {
                    f32x2 xs = (f32x2){X[j + k], X[j + k]};
                    acc0[j] += w0 * xs;
                    acc1[j] += w1v * xs;
                    acc2[j] += w2v * xs;
                }
            }
        }
        #pragma unroll
        for (int j = 0; j < 12; ++j) {
            int t = t0 + j;
            float sx = acc1[j].x + bb2x; sx = 1.f / (1.f + __expf(-sx));
            float sy = acc1[j].y + bb2y; sy = 1.f / (1.f + __expf(-sy));
            float ox = fmaxf(acc0[j].x + bb1x + sx + acc2[j].x + bb3x, 0.f);
            float oy = fmaxf(acc0[j].y + bb1y + sy + acc2[j].y + bb3y, 0.f);
            bool valid = (t < 94);
            stash[(c0 * 96 + t) * 8 + vv]       = valid ? f2bf(ox) : (unsigned short)0;
            stash[((c0 + 1) * 96 + t) * 8 + vv] = valid ? f2bf(oy) : (unsigned short)0;
        }
    }
    __syncthreads();

    // store: contiguous 1536B runs per channel
    for (int s = 0; s < 6; ++s) {
        int g = tid + s * 512;            // 0..3071 : 16B groups
        int c = g / 96, l = g % 96;
        uint4 val = *(const uint4*)&stash[(c * 96 + l) * 8];
        size_t b = (size_t)n * 32 + c;
        *(uint4*)((unsigned short*)xt + ((b * 64 + vblk) * 96 + l) * 8) = val;
    }
}

// ---------------------------------------------------------------------------
// hop: dst[b][w][l] = sum_v At[w][v] * src[b][v][l]   (bf16 MFMA 16x16x32)
// Block tile 128(w) x 96(l), K=512 in chunks of 32. 4 waves, 64x48 per wave.
// ---------------------------------------------------------------------------
__global__ __launch_bounds__(256)
void hop_kernel(const unsigned short* __restrict__ At,
                const unsigned short* __restrict__ src,
                unsigned short* __restrict__ dst)
{
    __shared__ unsigned short Ash[128 * 4 * 8];  // 8KB: [row][slot][8]
    __shared__ unsigned short Bsh[96 * 4 * 8];   // 6KB

    const int mtile = blockIdx.x;                // 0..3
    const int b = blockIdx.y;                    // 0..1023
    const int tid = threadIdx.x;
    const int lane = tid & 63, wv = tid >> 6;
    const int mhalf = (wv & 1) * 64, nhalf = (wv >> 1) * 48;
    const int col = lane & 15, q4 = lane >> 4;

    f32x4 acc[4][3];
    #pragma unroll
    for (int mt = 0; mt < 4; ++mt)
        #pragma unroll
        for (int nt = 0; nt < 3; ++nt)
            acc[mt][nt] = (f32x4){0.f, 0.f, 0.f, 0.f};

    const unsigned short* Abase = At + (size_t)(mtile * 128) * 512;
    const unsigned short* Bbase = src + (size_t)b * 64 * 96 * 8;

    for (int kc = 0; kc < 16; ++kc) {
        __syncthreads();
        #pragma unroll
        for (int t2 = 0; t2 < 2; ++t2) {
            int idx = tid + t2 * 256;
            int r = idx >> 2, q = idx & 3;
            uint4 val = *(const uint4*)(Abase + (size_t)r * 512 + kc * 32 + q * 8);
            *(uint4*)&Ash[(r * 4 + swz(r, q)) * 8] = val;
        }
        for (int g = tid; g < 384; g += 256) {
            int q = g / 96, l = g % 96;
            uint4 val = *(const uint4*)(Bbase + ((size_t)(kc * 4 + q) * 96 + l) * 8);
            *(uint4*)&Bsh[(l * 4 + swz(l, q)) * 8] = val;
        }
        __syncthreads();

        bf16x8 af[4], bfr[3];
        #pragma unroll
        for (int mt = 0; mt < 4; ++mt) {
            int r = mhalf + mt * 16 + col;
            af[mt] = *(const bf16x8*)&Ash[(r * 4 + swz(r, q4)) * 8];
        }
        #pragma unroll
        for (int nt = 0; nt < 3; ++nt) {
            int l = nhalf + nt * 16 + col;
            bfr[nt] = *(const bf16x8*)&Bsh[(l * 4 + swz(l, q4)) * 8];
        }
        #pragma unroll
        for (int mt = 0; mt < 4; ++mt)
            #pragma unroll
            for (int nt = 0; nt < 3; ++nt)
                acc[mt][nt] = __builtin_amdgcn_mfma_f32_16x16x32_bf16(
                    af[mt], bfr[nt], acc[mt][nt], 0, 0, 0);
    }

    // C/D layout: col = lane&15 (n=l), row = q4*4+reg (m=w). 4 regs = 4 consecutive w.
    #pragma unroll
    for (int mt = 0; mt < 4; ++mt) {
        int w0 = mtile * 128 + mhalf + mt * 16 + q4 * 4;
        int vblk = w0 >> 3, vv0 = w0 & 7;   // vv0 in {0,4}
        #pragma unroll
        for (int nt = 0; nt < 3; ++nt) {
            int l = nhalf + nt * 16 + col;
            uint2 u;
            u.x = (unsigned)f2bf(acc[mt][nt].x) | ((unsigned)f2bf(acc[mt][nt].y) << 16);
            u.y = (unsigned)f2bf(acc[mt][nt].z) | ((unsigned)f2bf(acc[mt][nt].w) << 16);
            *(uint2*)(dst + (((size_t)b * 64 + vblk) * 96 + l) * 8 + vv0) = u;
        }
    }
}

// ---------------------------------------------------------------------------
// proj: out[n][o][v][l] = PReLU(sum_c Wo[o][c]*h[c][v][l] + bout[o])
// h planes: c<32 -> xt, <64 -> x1, else x2. Block = (n, vblk, lq): 64 o x 128
// cols (col = vv*16 + ll so fp32 stores are 64B-contiguous in l).
// ---------------------------------------------------------------------------
__global__ __launch_bounds__(256)
void proj_kernel(const unsigned short* __restrict__ Wo,
                 const unsigned short* __restrict__ xt,
                 const unsigned short* __restrict__ x1,
                 const unsigned short* __restrict__ x2,
                 const float* __restrict__ bout,
                 const float* __restrict__ prelu_a,
                 float* __restrict__ out)
{
    __shared__ unsigned short WoSh[64 * 12 * 8]; // 12KB: [o][slot(12)][8]
    __shared__ unsigned short Bsh[128 * 4 * 8];  // 8KB:  [col][slot][8]

    const int lq = blockIdx.x;    // 0..5
    const int vblk = blockIdx.y;  // 0..62
    const int n = blockIdx.z;     // 0..31
    const int tid = threadIdx.x;
    const int lane = tid & 63, wv = tid >> 6;
    const int nbase = wv * 32;
    const int colL = lane & 15, q4 = lane >> 4;

    for (int g = tid; g < 768; g += 256) {
        int o = g / 12, slot = g % 12;
        int kc = slot >> 2, qq = slot & 3;
        uint4 val = *(const uint4*)(Wo + o * 96 + slot * 8);
        *(uint4*)&WoSh[(o * 12 + kc * 4 + swz(o, qq)) * 8] = val;
    }

    f32x4 acc[4][2];
    #pragma unroll
    for (int mt = 0; mt < 4; ++mt) { acc[mt][0] = (f32x4){0.f,0.f,0.f,0.f}; acc[mt][1] = (f32x4){0.f,0.f,0.f,0.f}; }

    const unsigned short* planes[3] = {xt, x1, x2};
    for (int kc = 0; kc < 3; ++kc) {
        __syncthreads();
        const unsigned short* P = planes[kc];
        // stage + transpose: 512 reads of 16B (c, ll, vv0..7) -> scatter to Bsh[col][c]
        #pragma unroll
        for (int t2 = 0; t2 < 2; ++t2) {
            int idx = tid + t2 * 256;
            int cl = idx >> 4, ll = idx & 15;     // c_local 0..31, ll 0..15
            union { uint4 u; unsigned short s[8]; } val;
            val.u = *(const uint4*)(P + (((size_t)(n * 32 + cl)) * 64 + vblk) * 96 * 8
                                      + (size_t)(lq * 16 + ll) * 8);
            int cq = cl >> 3, cw = cl & 7;
            #pragma unroll
            for (int vv = 0; vv < 8; ++vv) {
                int colv = vv * 16 + ll;
                Bsh[(colv * 4 + swz(colv, cq)) * 8 + cw] = val.s[vv];
            }
        }
        __syncthreads();

        bf16x8 af[4], bfr[2];
        #pragma unroll
        for (int mt = 0; mt < 4; ++mt) {
            int o = mt * 16 + colL;
            af[mt] = *(const bf16x8*)&WoSh[(o * 12 + kc * 4 + swz(o, q4)) * 8];
        }
        #pragma unroll
        for (int nt = 0; nt < 2; ++nt) {
            int colv = nbase + nt * 16 + colL;
            bfr[nt] = *(const bf16x8*)&Bsh[(colv * 4 + swz(colv, q4)) * 8];
        }
        #pragma unroll
        for (int mt = 0; mt < 4; ++mt)
            #pragma unroll
            for (int nt = 0; nt < 2; ++nt)
                acc[mt][nt] = __builtin_amdgcn_mfma_f32_16x16x32_bf16(
                    af[mt], bfr[nt], acc[mt][nt], 0, 0, 0);
    }

    const float pa = prelu_a[0];
    #pragma unroll
    for (int mt = 0; mt < 4; ++mt) {
        #pragma unroll
        for (int nt = 0; nt < 2; ++nt) {
            #pragma unroll
            for (int r = 0; r < 4; ++r) {
                int o = mt * 16 + q4 * 4 + r;
                int colv = nbase + nt * 16 + colL;
                int vv = colv >> 4, ll = colv & 15;
                int v = vblk * 8 + vv, l = lq * 16 + ll;
                if (v < 500 && l < 94) {
                    float val = acc[mt][nt][r] + bout[o];
                    val = (val > 0.f) ? val : pa * val;
                    out[(((size_t)n * 64 + o) * 500 + v) * 94 + l] = val;
                }
            }
        }
    }
}

// ---------------------------------------------------------------------------
extern "C" void kernel_launch(void* const* d_in, const int* in_sizes, int n_in,
                              void* d_out, int out_size, void* d_ws, size_t ws_size,
                              hipStream_t stream)
{
    const float* x    = (const float*)d_in[0];
    const float* A    = (const float*)d_in[1];
    const float* w1   = (const float*)d_in[2];
    const float* b1   = (const float*)d_in[3];
    const float* w2   = (const float*)d_in[4];
    const float* b2   = (const float*)d_in[5];
    const float* w3   = (const float*)d_in[6];
    const float* b3   = (const float*)d_in[7];
    const float* wout = (const float*)d_in[8];
    const float* bout = (const float*)d_in[9];
    const float* pa   = (const float*)d_in[10];
    float* out = (float*)d_out;

    char* ws = (char*)d_ws;
    unsigned short* xt = (unsigned short*)(ws);
    unsigned short* x1 = (unsigned short*)(ws + WS_S);
    unsigned short* x2 = (unsigned short*)(ws + 2 * WS_S);
    unsigned short* At = (unsigned short*)(ws + 3 * WS_S);
    float* Wp          = (float*)(ws + 3 * WS_S + AT_B);
    unsigned short* Wo = (unsigned short*)(ws + 3 * WS_S + AT_B + WP_B);

    const int prep_elems = 512 * 512 + 32 * 3 * 3 * 32 + 64 * 96;
    prep_kernel<<<dim3((prep_elems + 255) / 256), 256, 0, stream>>>(
        A, w1, w2, w3, wout, At, Wp, Wo);
    conv_kernel<<<dim3(63, 32), 512, 0, stream>>>(x, Wp, b1, b2, b3, xt);
    hop_kernel<<<dim3(4, 1024), 256, 0, stream>>>(At, xt, x1);
    hop_kernel<<<dim3(4, 1024), 256, 0, stream>>>(At, x1, x2);
    proj_kernel<<<dim3(6, 63, 32), 256, 0, stream>>>(Wo, xt, x1, x2, bout, pa, out);
}